// Round 1
// baseline (502.009 us; speedup 1.0000x reference)
//
#include <hip/hip_runtime.h>
#include <hip/hip_bf16.h>
#include <math.h>

#define F_IN 256
#define HEADS 8
#define CPH 32
#define NEG_SLOPE 0.2f

// ---------------------------------------------------------------------------
// GEMM: H = X[M,256] @ W[256,256], fp32, 64x64 tile, BK=16, 4x4 micro-tile
// ---------------------------------------------------------------------------
__global__ __launch_bounds__(256) void gemm_kernel(
    const float* __restrict__ X, const float* __restrict__ Wm,
    float* __restrict__ H, int M)
{
    __shared__ float As[16][64];
    __shared__ float Bs[16][64];
    const int tid = threadIdx.x;
    const int tx = tid & 15;        // 0..15  -> col group
    const int ty = tid >> 4;        // 0..15  -> row group
    const int row0 = blockIdx.x * 64;
    const int col0 = blockIdx.y * 64;

    // A-load mapping: thread loads float4 of X[row0+la_m][k0+la_k .. +3]
    const int la_m = tid >> 2;          // 0..63
    const int la_k = (tid & 3) * 4;     // 0,4,8,12
    // B-load mapping: thread loads float4 of W[k0+lb_k][col0+lb_n .. +3]
    const int lb_k = tid >> 4;          // 0..15
    const int lb_n = (tid & 15) * 4;    // 0..60

    float acc[4][4] = {};

    for (int k0 = 0; k0 < F_IN; k0 += 16) {
        float4 av = make_float4(0.f, 0.f, 0.f, 0.f);
        const int r = row0 + la_m;
        if (r < M) av = *(const float4*)(X + (size_t)r * F_IN + k0 + la_k);
        As[la_k + 0][la_m] = av.x;
        As[la_k + 1][la_m] = av.y;
        As[la_k + 2][la_m] = av.z;
        As[la_k + 3][la_m] = av.w;
        const float4 bv = *(const float4*)(Wm + (size_t)(k0 + lb_k) * 256 + col0 + lb_n);
        *(float4*)&Bs[lb_k][lb_n] = bv;
        __syncthreads();
#pragma unroll
        for (int kk = 0; kk < 16; ++kk) {
            const float4 a = *(const float4*)&As[kk][ty * 4];
            const float4 b = *(const float4*)&Bs[kk][tx * 4];
            acc[0][0] += a.x * b.x; acc[0][1] += a.x * b.y; acc[0][2] += a.x * b.z; acc[0][3] += a.x * b.w;
            acc[1][0] += a.y * b.x; acc[1][1] += a.y * b.y; acc[1][2] += a.y * b.z; acc[1][3] += a.y * b.w;
            acc[2][0] += a.z * b.x; acc[2][1] += a.z * b.y; acc[2][2] += a.z * b.z; acc[2][3] += a.z * b.w;
            acc[3][0] += a.w * b.x; acc[3][1] += a.w * b.y; acc[3][2] += a.w * b.z; acc[3][3] += a.w * b.w;
        }
        __syncthreads();
    }

#pragma unroll
    for (int i = 0; i < 4; ++i) {
        const int row = row0 + ty * 4 + i;
        if (row < M) {
            float4 o = make_float4(acc[i][0], acc[i][1], acc[i][2], acc[i][3]);
            *(float4*)(H + (size_t)row * 256 + col0 + tx * 4) = o;
        }
    }
}

// ---------------------------------------------------------------------------
// Per-node attention logits: a_src[n,h] = dot(h[n,h,:], att_src[h,:]) etc.
// One wave per node; lane covers channels 4l..4l+3 (head = l>>3).
// att vectors are flat [H*C]=256 floats, aligned with channel index.
// ---------------------------------------------------------------------------
__global__ __launch_bounds__(256) void attdot_kernel(
    const float* __restrict__ H, const float* __restrict__ att_src,
    const float* __restrict__ att_dst, float* __restrict__ a_src,
    float* __restrict__ a_dst, int N)
{
    const int n = (int)((blockIdx.x * blockDim.x + threadIdx.x) >> 6);
    const int lane = threadIdx.x & 63;
    if (n >= N) return;
    const float4 hv = *(const float4*)(H + (size_t)n * 256 + lane * 4);
    const float4 as = *(const float4*)(att_src + lane * 4);
    const float4 ad = *(const float4*)(att_dst + lane * 4);
    float s = hv.x * as.x + hv.y * as.y + hv.z * as.z + hv.w * as.w;
    float d = hv.x * ad.x + hv.y * ad.y + hv.z * ad.z + hv.w * ad.w;
#pragma unroll
    for (int off = 1; off < 8; off <<= 1) {
        s += __shfl_xor(s, off);
        d += __shfl_xor(d, off);
    }
    if ((lane & 7) == 0) {
        a_src[(size_t)n * 8 + (lane >> 3)] = s;
        a_dst[(size_t)n * 8 + (lane >> 3)] = d;
    }
}

// ---------------------------------------------------------------------------
// Degree histogram over E2 = E + N edges (self-loops appended)
// ---------------------------------------------------------------------------
__global__ __launch_bounds__(256) void hist_kernel(
    const int* __restrict__ ei, int* __restrict__ deg, int E, int E2)
{
    const int e = blockIdx.x * blockDim.x + threadIdx.x;
    if (e >= E2) return;
    const int dst = (e < E) ? ei[(size_t)E + e] : (e - E);
    atomicAdd(&deg[dst], 1);
}

// ---------------------------------------------------------------------------
// Exclusive scan of deg[0..n) -> offsets[0..n]; single block, Hillis-Steele
// ---------------------------------------------------------------------------
__global__ __launch_bounds__(1024) void scan_kernel(
    const int* __restrict__ deg, int* __restrict__ offsets, int n)
{
    __shared__ int tmp[1024];
    __shared__ int s_carry;
    if (threadIdx.x == 0) s_carry = 0;
    __syncthreads();
    for (int base = 0; base < n; base += 1024) {
        const int i = base + (int)threadIdx.x;
        const int v = (i < n) ? deg[i] : 0;
        tmp[threadIdx.x] = v;
        __syncthreads();
        int x = v;
        for (int off = 1; off < 1024; off <<= 1) {
            int add = 0;
            if ((int)threadIdx.x >= off) add = tmp[threadIdx.x - off];
            __syncthreads();
            x += add;
            tmp[threadIdx.x] = x;
            __syncthreads();
        }
        const int carry = s_carry;
        if (i < n) offsets[i] = carry + x - v;   // exclusive
        __syncthreads();
        if (threadIdx.x == 1023) s_carry = carry + x;  // + chunk total
        __syncthreads();
    }
    if (threadIdx.x == 0) offsets[n] = s_carry;
}

// ---------------------------------------------------------------------------
// Scatter edges into CSR order (counting sort by dst)
// ---------------------------------------------------------------------------
__global__ __launch_bounds__(256) void scatter_kernel(
    const int* __restrict__ ei, const int* __restrict__ offsets,
    int* __restrict__ cursor, int* __restrict__ sorted_src, int E, int E2)
{
    const int e = blockIdx.x * blockDim.x + threadIdx.x;
    if (e >= E2) return;
    int src, dst;
    if (e < E) { src = ei[e]; dst = ei[(size_t)E + e]; }
    else       { src = e - E; dst = e - E; }
    const int pos = atomicAdd(&cursor[dst], 1);
    sorted_src[offsets[dst] + pos] = src;
}

// ---------------------------------------------------------------------------
// Aggregate: one wave per dst node. 3 phases: per-head max, per-head sum of
// exp, weighted accumulate of h[src]. Then bias + ELU, coalesced float4 write.
// Phases 1-2: lane handles head (lane&7), edges strided by 8.
// Phase 3:    lane handles channels 4*lane..4*lane+3 -> head (lane>>3).
// ---------------------------------------------------------------------------
__global__ __launch_bounds__(256) void aggregate_kernel(
    const float* __restrict__ H, const float* __restrict__ Asrc,
    const float* __restrict__ Adst, const int* __restrict__ offsets,
    const int* __restrict__ sorted_src, const float* __restrict__ bias,
    float* __restrict__ out, int N)
{
    const int n = (int)((blockIdx.x * blockDim.x + threadIdx.x) >> 6);
    const int lane = threadIdx.x & 63;
    if (n >= N) return;

    const int beg = offsets[n];
    const int deg = offsets[n + 1] - beg;

    const int h2 = lane & 7;
    const float adst2 = Adst[(size_t)n * 8 + h2];

    // phase 1: per-head max of leaky_relu(a_src+a_dst)
    float maxv = -INFINITY;
    for (int i = lane; i < deg * 8; i += 64) {
        const int s = sorted_src[beg + (i >> 3)];
        float a = Asrc[(size_t)s * 8 + h2] + adst2;
        a = a > 0.f ? a : NEG_SLOPE * a;
        maxv = fmaxf(maxv, a);
    }
#pragma unroll
    for (int off = 8; off < 64; off <<= 1) maxv = fmaxf(maxv, __shfl_xor(maxv, off));

    // phase 2: per-head sum of exp(alpha - max)
    float dsum = 0.f;
    for (int i = lane; i < deg * 8; i += 64) {
        const int s = sorted_src[beg + (i >> 3)];
        float a = Asrc[(size_t)s * 8 + h2] + adst2;
        a = a > 0.f ? a : NEG_SLOPE * a;
        dsum += expf(a - maxv);
    }
#pragma unroll
    for (int off = 8; off < 64; off <<= 1) dsum += __shfl_xor(dsum, off);

    // redistribute to phase-3 head (lane>>3)
    const int h3 = lane >> 3;
    const float m3 = __shfl(maxv, h3);
    const float d3 = __shfl(dsum, h3);
    const float adst3 = __shfl(adst2, h3);
    const float rdn = 1.f / (d3 + 1e-16f);

    // phase 3: acc = sum_e attn(e) * h[src_e][4l..4l+3]
    float4 acc = make_float4(0.f, 0.f, 0.f, 0.f);
    for (int e = 0; e < deg; ++e) {
        const int s = sorted_src[beg + e];
        float a = Asrc[(size_t)s * 8 + h3] + adst3;
        a = a > 0.f ? a : NEG_SLOPE * a;
        const float w = expf(a - m3) * rdn;
        const float4 hv = *(const float4*)(H + (size_t)s * 256 + lane * 4);
        acc.x += hv.x * w; acc.y += hv.y * w; acc.z += hv.z * w; acc.w += hv.w * w;
    }

    const float4 b = *(const float4*)(bias + lane * 4);
    float4 o;
    o.x = acc.x + b.x; o.y = acc.y + b.y; o.z = acc.z + b.z; o.w = acc.w + b.w;
    o.x = o.x > 0.f ? o.x : expf(o.x) - 1.f;
    o.y = o.y > 0.f ? o.y : expf(o.y) - 1.f;
    o.z = o.z > 0.f ? o.z : expf(o.z) - 1.f;
    o.w = o.w > 0.f ? o.w : expf(o.w) - 1.f;
    *(float4*)(out + (size_t)n * 256 + lane * 4) = o;
}

// ---------------------------------------------------------------------------
extern "C" void kernel_launch(void* const* d_in, const int* in_sizes, int n_in,
                              void* d_out, int out_size, void* d_ws, size_t ws_size,
                              hipStream_t stream)
{
    const float* x       = (const float*)d_in[0];
    const int*   ei      = (const int*)  d_in[1];
    const float* W       = (const float*)d_in[2];
    const float* att_src = (const float*)d_in[3];
    const float* att_dst = (const float*)d_in[4];
    const float* bias    = (const float*)d_in[5];
    float* out = (float*)d_out;

    const int N  = in_sizes[0] / F_IN;   // 50000
    const int E  = in_sizes[1] / 2;      // 800000
    const int E2 = E + N;                // + self loops

    // workspace layout (256B aligned sections)
    char* ws = (char*)d_ws;
    size_t o = 0;
    auto take = [&](size_t bytes) { void* p = ws + o; o = (o + bytes + 255) & ~(size_t)255; return p; };
    float* H          = (float*)take((size_t)N * 256 * 4);  // 51.2 MB
    float* a_src      = (float*)take((size_t)N * 8 * 4);
    float* a_dst      = (float*)take((size_t)N * 8 * 4);
    int*   deg        = (int*)  take((size_t)N * 4 * 2);    // deg + cursor adjacent
    int*   cursor     = deg + N;
    int*   offsets    = (int*)  take((size_t)(N + 1) * 4);
    int*   sorted_src = (int*)  take((size_t)E2 * 4);
    (void)ws_size; (void)n_in; (void)out_size;

    // 0) zero deg + cursor (ws is poisoned 0xAA before every call)
    hipMemsetAsync(deg, 0, (size_t)N * 4 * 2, stream);

    // 1) H = x @ W
    dim3 ggrid((N + 63) / 64, 4);
    gemm_kernel<<<ggrid, 256, 0, stream>>>(x, W, H, N);

    // 2) attention logits per node/head
    attdot_kernel<<<(N * 64 + 255) / 256, 256, 0, stream>>>(H, att_src, att_dst, a_src, a_dst, N);

    // 3) CSR build: histogram -> scan -> scatter
    hist_kernel<<<(E2 + 255) / 256, 256, 0, stream>>>(ei, deg, E, E2);
    scan_kernel<<<1, 1024, 0, stream>>>(deg, offsets, N);
    scatter_kernel<<<(E2 + 255) / 256, 256, 0, stream>>>(ei, offsets, cursor, sorted_src, E, E2);

    // 4) softmax + aggregate + bias + ELU
    aggregate_kernel<<<(N * 64 + 255) / 256, 256, 0, stream>>>(H, a_src, a_dst, offsets, sorted_src, bias, out, N);
}

// Round 2
// 480.228 us; speedup vs baseline: 1.0454x; 1.0454x over previous
//
#include <hip/hip_runtime.h>
#include <hip/hip_bf16.h>
#include <math.h>

#define F_IN 256
#define HEADS 8
#define CPH 32
#define NEG_SLOPE 0.2f

// ---------------------------------------------------------------------------
// GEMM: H = X[M,256] @ W[256,256], fp32, 128x128 tile, BK=16, 8x8 micro-tile
// ---------------------------------------------------------------------------
#define BM 128
#define BN 128
#define BK 16
__global__ __launch_bounds__(256) void gemm_kernel(
    const float* __restrict__ X, const float* __restrict__ Wm,
    float* __restrict__ H, int M)
{
    __shared__ float As[BK][BM];   // transposed: As[k][m]
    __shared__ float Bs[BK][BN];   // Bs[k][n]
    const int tid = threadIdx.x;
    const int tx = tid & 15;        // 0..15 -> col group (8 cols)
    const int ty = tid >> 4;        // 0..15 -> row group (8 rows)
    const int row0 = blockIdx.x * BM;
    const int col0 = blockIdx.y * BN;

    float acc[8][8] = {};

    for (int k0 = 0; k0 < F_IN; k0 += BK) {
#pragma unroll
        for (int rep = 0; rep < 2; ++rep) {
            const int f = tid + rep * 256;
            // A: 128x16 tile = 512 float4s. f -> row=f>>2, k=(f&3)*4
            const int ar = f >> 2;
            const int ak = (f & 3) * 4;
            float4 av = make_float4(0.f, 0.f, 0.f, 0.f);
            if (row0 + ar < M)
                av = *(const float4*)(X + (size_t)(row0 + ar) * F_IN + k0 + ak);
            As[ak + 0][ar] = av.x;
            As[ak + 1][ar] = av.y;
            As[ak + 2][ar] = av.z;
            As[ak + 3][ar] = av.w;
            // B: 16x128 tile = 512 float4s. f -> k=f>>5, n=(f&31)*4
            const int bk = f >> 5;
            const int bn = (f & 31) * 4;
            const float4 bv = *(const float4*)(Wm + (size_t)(k0 + bk) * 256 + col0 + bn);
            *(float4*)&Bs[bk][bn] = bv;
        }
        __syncthreads();
#pragma unroll
        for (int kk = 0; kk < BK; ++kk) {
            float a[8], b[8];
            const float4 a0 = *(const float4*)&As[kk][ty * 8];
            const float4 a1 = *(const float4*)&As[kk][ty * 8 + 4];
            const float4 b0 = *(const float4*)&Bs[kk][tx * 8];
            const float4 b1 = *(const float4*)&Bs[kk][tx * 8 + 4];
            a[0] = a0.x; a[1] = a0.y; a[2] = a0.z; a[3] = a0.w;
            a[4] = a1.x; a[5] = a1.y; a[6] = a1.z; a[7] = a1.w;
            b[0] = b0.x; b[1] = b0.y; b[2] = b0.z; b[3] = b0.w;
            b[4] = b1.x; b[5] = b1.y; b[6] = b1.z; b[7] = b1.w;
#pragma unroll
            for (int i = 0; i < 8; ++i)
#pragma unroll
                for (int j = 0; j < 8; ++j)
                    acc[i][j] += a[i] * b[j];
        }
        __syncthreads();
    }

#pragma unroll
    for (int i = 0; i < 8; ++i) {
        const int row = row0 + ty * 8 + i;
        if (row < M) {
            float4 o0 = make_float4(acc[i][0], acc[i][1], acc[i][2], acc[i][3]);
            float4 o1 = make_float4(acc[i][4], acc[i][5], acc[i][6], acc[i][7]);
            *(float4*)(H + (size_t)row * 256 + col0 + tx * 8)     = o0;
            *(float4*)(H + (size_t)row * 256 + col0 + tx * 8 + 4) = o1;
        }
    }
}

// ---------------------------------------------------------------------------
// Per-node attention logits: a_src[n,h] = dot(h[n,h,:], att_src[h,:]) etc.
// ---------------------------------------------------------------------------
__global__ __launch_bounds__(256) void attdot_kernel(
    const float* __restrict__ H, const float* __restrict__ att_src,
    const float* __restrict__ att_dst, float* __restrict__ a_src,
    float* __restrict__ a_dst, int N)
{
    const int n = (int)((blockIdx.x * blockDim.x + threadIdx.x) >> 6);
    const int lane = threadIdx.x & 63;
    if (n >= N) return;
    const float4 hv = *(const float4*)(H + (size_t)n * 256 + lane * 4);
    const float4 as = *(const float4*)(att_src + lane * 4);
    const float4 ad = *(const float4*)(att_dst + lane * 4);
    float s = hv.x * as.x + hv.y * as.y + hv.z * as.z + hv.w * as.w;
    float d = hv.x * ad.x + hv.y * ad.y + hv.z * ad.z + hv.w * ad.w;
#pragma unroll
    for (int off = 1; off < 8; off <<= 1) {
        s += __shfl_xor(s, off);
        d += __shfl_xor(d, off);
    }
    if ((lane & 7) == 0) {
        a_src[(size_t)n * 8 + (lane >> 3)] = s;
        a_dst[(size_t)n * 8 + (lane >> 3)] = d;
    }
}

// ---------------------------------------------------------------------------
// Degree histogram over E2 = E + N edges (self-loops appended)
// ---------------------------------------------------------------------------
__global__ __launch_bounds__(256) void hist_kernel(
    const int* __restrict__ ei, int* __restrict__ deg, int E, int E2)
{
    const int e = blockIdx.x * blockDim.x + threadIdx.x;
    if (e >= E2) return;
    const int dst = (e < E) ? ei[(size_t)E + e] : (e - E);
    atomicAdd(&deg[dst], 1);
}

// ---------------------------------------------------------------------------
// Hierarchical exclusive scan (3 kernels): reduce -> scan partials -> final
// ---------------------------------------------------------------------------
__global__ __launch_bounds__(256) void scan_reduce_kernel(
    const int* __restrict__ deg, int* __restrict__ partial, int n)
{
    const int i = blockIdx.x * 256 + threadIdx.x;
    int v = (i < n) ? deg[i] : 0;
#pragma unroll
    for (int off = 1; off < 64; off <<= 1) v += __shfl_xor(v, off);
    __shared__ int s[4];
    if ((threadIdx.x & 63) == 0) s[threadIdx.x >> 6] = v;
    __syncthreads();
    if (threadIdx.x == 0) partial[blockIdx.x] = s[0] + s[1] + s[2] + s[3];
}

__global__ __launch_bounds__(256) void scan_partials_kernel(
    int* __restrict__ partial, int nb)
{
    __shared__ int tmp[256];
    const int t = threadIdx.x;
    const int v = (t < nb) ? partial[t] : 0;
    tmp[t] = v;
    __syncthreads();
    for (int off = 1; off < 256; off <<= 1) {
        int add = (t >= off) ? tmp[t - off] : 0;
        __syncthreads();
        tmp[t] += add;
        __syncthreads();
    }
    if (t < nb) partial[t] = tmp[t] - v;   // exclusive
}

__global__ __launch_bounds__(256) void scan_final_kernel(
    const int* __restrict__ deg, const int* __restrict__ partial,
    int* __restrict__ offsets, int n, int total)
{
    __shared__ int tmp[256];
    const int t = threadIdx.x;
    const int i = blockIdx.x * 256 + t;
    const int v = (i < n) ? deg[i] : 0;
    tmp[t] = v;
    __syncthreads();
    for (int off = 1; off < 256; off <<= 1) {
        int add = (t >= off) ? tmp[t - off] : 0;
        __syncthreads();
        tmp[t] += add;
        __syncthreads();
    }
    if (i < n) offsets[i] = partial[blockIdx.x] + tmp[t] - v;
    if (i == 0) offsets[n] = total;
}

// ---------------------------------------------------------------------------
// Scatter edges into CSR order (counting sort by dst)
// ---------------------------------------------------------------------------
__global__ __launch_bounds__(256) void scatter_kernel(
    const int* __restrict__ ei, const int* __restrict__ offsets,
    int* __restrict__ cursor, int* __restrict__ sorted_src, int E, int E2)
{
    const int e = blockIdx.x * blockDim.x + threadIdx.x;
    if (e >= E2) return;
    int src, dst;
    if (e < E) { src = ei[e]; dst = ei[(size_t)E + e]; }
    else       { src = e - E; dst = e - E; }
    const int pos = atomicAdd(&cursor[dst], 1);
    sorted_src[offsets[dst] + pos] = src;
}

// ---------------------------------------------------------------------------
// Aggregate: one wave per dst node.
// Phase A (online softmax): lane handles head (lane&7), edges strided by 8;
//   running (max, sum) merged across the 8 lanes per head via shfl butterfly.
// Phase B: lane handles channels 4*lane..+3 -> head (lane>>3); unroll 2.
// ---------------------------------------------------------------------------
__global__ __launch_bounds__(256) void aggregate_kernel(
    const float* __restrict__ H, const float* __restrict__ Asrc,
    const float* __restrict__ Adst, const int* __restrict__ offsets,
    const int* __restrict__ sorted_src, const float* __restrict__ bias,
    float* __restrict__ out, int N)
{
    const int n = (int)((blockIdx.x * blockDim.x + threadIdx.x) >> 6);
    const int lane = threadIdx.x & 63;
    if (n >= N) return;

    const int beg = offsets[n];
    const int deg = offsets[n + 1] - beg;

    const int h2 = lane & 7;
    const float adst2 = Adst[(size_t)n * 8 + h2];

    // phase A: online per-head (max, sum-of-exp)
    float m = -INFINITY;
    float ssum = 0.f;
    for (int i = lane; i < deg * 8; i += 64) {
        const int s = sorted_src[beg + (i >> 3)];
        float a = Asrc[(size_t)s * 8 + h2] + adst2;
        a = a > 0.f ? a : NEG_SLOPE * a;
        if (a > m) { ssum *= expf(m - a); m = a; }
        ssum += expf(a - m);
    }
#pragma unroll
    for (int off = 8; off < 64; off <<= 1) {
        const float mo = __shfl_xor(m, off);
        const float so = __shfl_xor(ssum, off);
        const float mn = fmaxf(m, mo);
        const float f1 = (m  <= -INFINITY) ? 0.f : expf(m  - mn);
        const float f2 = (mo <= -INFINITY) ? 0.f : expf(mo - mn);
        ssum = ssum * f1 + so * f2;
        m = mn;
    }

    // redistribute to phase-B head (lane>>3)
    const int h3 = lane >> 3;
    const float m3 = __shfl(m, h3);
    const float d3 = __shfl(ssum, h3);
    const float adst3 = __shfl(adst2, h3);
    const float rdn = 1.f / (d3 + 1e-16f);

    // phase B: acc = sum_e attn(e) * h[src_e][4l..4l+3], unrolled by 2
    float4 acc0 = make_float4(0.f, 0.f, 0.f, 0.f);
    float4 acc1 = make_float4(0.f, 0.f, 0.f, 0.f);
    int e = 0;
    for (; e + 2 <= deg; e += 2) {
        const int s0 = sorted_src[beg + e];
        const int s1 = sorted_src[beg + e + 1];
        float a0 = Asrc[(size_t)s0 * 8 + h3] + adst3;
        float a1 = Asrc[(size_t)s1 * 8 + h3] + adst3;
        a0 = a0 > 0.f ? a0 : NEG_SLOPE * a0;
        a1 = a1 > 0.f ? a1 : NEG_SLOPE * a1;
        const float w0 = expf(a0 - m3) * rdn;
        const float w1 = expf(a1 - m3) * rdn;
        const float4 h0 = *(const float4*)(H + (size_t)s0 * 256 + lane * 4);
        const float4 h1 = *(const float4*)(H + (size_t)s1 * 256 + lane * 4);
        acc0.x += h0.x * w0; acc0.y += h0.y * w0; acc0.z += h0.z * w0; acc0.w += h0.w * w0;
        acc1.x += h1.x * w1; acc1.y += h1.y * w1; acc1.z += h1.z * w1; acc1.w += h1.w * w1;
    }
    if (e < deg) {
        const int s0 = sorted_src[beg + e];
        float a0 = Asrc[(size_t)s0 * 8 + h3] + adst3;
        a0 = a0 > 0.f ? a0 : NEG_SLOPE * a0;
        const float w0 = expf(a0 - m3) * rdn;
        const float4 h0 = *(const float4*)(H + (size_t)s0 * 256 + lane * 4);
        acc0.x += h0.x * w0; acc0.y += h0.y * w0; acc0.z += h0.z * w0; acc0.w += h0.w * w0;
    }
    float4 acc;
    acc.x = acc0.x + acc1.x; acc.y = acc0.y + acc1.y;
    acc.z = acc0.z + acc1.z; acc.w = acc0.w + acc1.w;

    const float4 b = *(const float4*)(bias + lane * 4);
    float4 o;
    o.x = acc.x + b.x; o.y = acc.y + b.y; o.z = acc.z + b.z; o.w = acc.w + b.w;
    o.x = o.x > 0.f ? o.x : expf(o.x) - 1.f;
    o.y = o.y > 0.f ? o.y : expf(o.y) - 1.f;
    o.z = o.z > 0.f ? o.z : expf(o.z) - 1.f;
    o.w = o.w > 0.f ? o.w : expf(o.w) - 1.f;
    *(float4*)(out + (size_t)n * 256 + lane * 4) = o;
}

// ---------------------------------------------------------------------------
extern "C" void kernel_launch(void* const* d_in, const int* in_sizes, int n_in,
                              void* d_out, int out_size, void* d_ws, size_t ws_size,
                              hipStream_t stream)
{
    const float* x       = (const float*)d_in[0];
    const int*   ei      = (const int*)  d_in[1];
    const float* W       = (const float*)d_in[2];
    const float* att_src = (const float*)d_in[3];
    const float* att_dst = (const float*)d_in[4];
    const float* bias    = (const float*)d_in[5];
    float* out = (float*)d_out;

    const int N  = in_sizes[0] / F_IN;   // 50000
    const int E  = in_sizes[1] / 2;      // 800000
    const int E2 = E + N;                // + self loops
    const int NB = (N + 255) / 256;      // scan blocks

    // workspace layout (256B aligned sections)
    char* ws = (char*)d_ws;
    size_t o = 0;
    auto take = [&](size_t bytes) { void* p = ws + o; o = (o + bytes + 255) & ~(size_t)255; return p; };
    float* H          = (float*)take((size_t)N * 256 * 4);  // 51.2 MB
    float* a_src      = (float*)take((size_t)N * 8 * 4);
    float* a_dst      = (float*)take((size_t)N * 8 * 4);
    int*   deg        = (int*)  take((size_t)N * 4 * 2);    // deg + cursor adjacent
    int*   cursor     = deg + N;
    int*   offsets    = (int*)  take((size_t)(N + 1) * 4);
    int*   sorted_src = (int*)  take((size_t)E2 * 4);
    int*   partial    = (int*)  take((size_t)NB * 4);
    (void)ws_size; (void)n_in; (void)out_size;

    // 0) zero deg + cursor (ws is poisoned 0xAA before every call)
    hipMemsetAsync(deg, 0, (size_t)N * 4 * 2, stream);

    // 1) H = x @ W
    dim3 ggrid((N + BM - 1) / BM, 256 / BN);
    gemm_kernel<<<ggrid, 256, 0, stream>>>(x, W, H, N);

    // 2) attention logits per node/head
    attdot_kernel<<<(N * 64 + 255) / 256, 256, 0, stream>>>(H, att_src, att_dst, a_src, a_dst, N);

    // 3) CSR build: histogram -> hierarchical scan -> scatter
    hist_kernel<<<(E2 + 255) / 256, 256, 0, stream>>>(ei, deg, E, E2);
    scan_reduce_kernel<<<NB, 256, 0, stream>>>(deg, partial, N);
    scan_partials_kernel<<<1, 256, 0, stream>>>(partial, NB);
    scan_final_kernel<<<NB, 256, 0, stream>>>(deg, partial, offsets, N, E2);
    scatter_kernel<<<(E2 + 255) / 256, 256, 0, stream>>>(ei, offsets, cursor, sorted_src, E, E2);

    // 4) softmax + aggregate + bias + ELU
    aggregate_kernel<<<(N * 64 + 255) / 256, 256, 0, stream>>>(H, a_src, a_dst, offsets, sorted_src, bias, out, N);
}

// Round 3
// 367.742 us; speedup vs baseline: 1.3651x; 1.3059x over previous
//
#include <hip/hip_runtime.h>
#include <hip/hip_bf16.h>
#include <math.h>

#define F_IN 256
#define HEADS 8
#define CPH 32
#define NEG_SLOPE 0.2f

typedef short bf16x8 __attribute__((ext_vector_type(8)));
typedef float f32x4  __attribute__((ext_vector_type(4)));

// fp32 -> bf16 (RNE) as raw ushort bits
static __device__ __forceinline__ unsigned short f2bf(float f) {
    union { float f; unsigned int u; } v; v.f = f;
    unsigned int r = (v.u + 0x7FFFu + ((v.u >> 16) & 1u)) >> 16;
    return (unsigned short)r;
}
static __device__ __forceinline__ float bf2f(unsigned short h) {
    union { unsigned int u; float f; } v; v.u = ((unsigned int)h) << 16;
    return v.f;
}

// ---------------------------------------------------------------------------
// W prep: split W[k][n] fp32 into hi/lo bf16, pre-tiled for GEMM B-staging:
// Wt[sel][step][kg][n][j] = bf16(W[step*32 + kg*8 + j][n]);  sel=hi/lo
// ---------------------------------------------------------------------------
__global__ __launch_bounds__(256) void wprep_kernel(
    const float* __restrict__ W, short* __restrict__ WtHi, short* __restrict__ WtLo)
{
    const int k = blockIdx.x;      // 0..255
    const int n = threadIdx.x;     // 0..255
    const float w = W[(size_t)k * 256 + n];
    const unsigned short h = f2bf(w);
    const unsigned short l = f2bf(w - bf2f(h));
    const int step = k >> 5, kg = (k >> 3) & 3, j = k & 7;
    const size_t dst = ((((size_t)step * 4 + kg) * 256) + n) * 8 + j;
    WtHi[dst] = (short)h;
    WtLo[dst] = (short)l;
}

// ---------------------------------------------------------------------------
// GEMM: H = X[M,256] @ W[256,256] via bf16x3-split MFMA (fp32-accurate).
// Block 256 thr = 4 waves (2x2), block tile 128x128, wave tile 64x64,
// K-step 32. LDS layout [kg][row][8 bf16], kg = k/8 = lane>>4.
// ---------------------------------------------------------------------------
__global__ __launch_bounds__(256, 2) void gemm_mfma_kernel(
    const float* __restrict__ X, const short* __restrict__ WtHi,
    const short* __restrict__ WtLo, float* __restrict__ H, int M)
{
    __shared__ short Ah[4][128][8];
    __shared__ short Al[4][128][8];
    __shared__ short Bh[4][128][8];
    __shared__ short Bl[4][128][8];

    const int t    = threadIdx.x;
    const int lane = t & 63;
    const int wid  = t >> 6;
    const int wr   = wid >> 1;          // wave row 0..1
    const int wc   = wid & 1;           // wave col 0..1
    const int row0 = blockIdx.x * 128;
    const int col0 = blockIdx.y * 128;

    const int srow  = t >> 1;           // staging row 0..127
    const int shalf = t & 1;            // which 16-k half

    f32x4 acc[4][4];
#pragma unroll
    for (int i = 0; i < 4; ++i)
#pragma unroll
        for (int j = 0; j < 4; ++j)
            acc[i][j] = (f32x4){0.f, 0.f, 0.f, 0.f};

    const int kgf = lane >> 4;          // fragment k-group
    const int lrow = lane & 15;

    for (int step = 0; step < 8; ++step) {
        const int k0 = step * 32;
        // ---- stage A (x split on the fly) ----
        float f[16];
        const int grow = row0 + srow;
        if (grow < M) {
            const float4* xp = (const float4*)(X + (size_t)grow * 256 + k0 + shalf * 16);
            const float4 v0 = xp[0], v1 = xp[1], v2 = xp[2], v3 = xp[3];
            f[0] = v0.x; f[1] = v0.y; f[2]  = v0.z; f[3]  = v0.w;
            f[4] = v1.x; f[5] = v1.y; f[6]  = v1.z; f[7]  = v1.w;
            f[8] = v2.x; f[9] = v2.y; f[10] = v2.z; f[11] = v2.w;
            f[12] = v3.x; f[13] = v3.y; f[14] = v3.z; f[15] = v3.w;
        } else {
#pragma unroll
            for (int j = 0; j < 16; ++j) f[j] = 0.f;
        }
#pragma unroll
        for (int c = 0; c < 2; ++c) {
            bf16x8 hi, lo;
#pragma unroll
            for (int j = 0; j < 8; ++j) {
                const float x = f[c * 8 + j];
                const unsigned short hb = f2bf(x);
                hi[j] = (short)hb;
                lo[j] = (short)f2bf(x - bf2f(hb));
            }
            const int kg = shalf * 2 + c;
            *(bf16x8*)&Ah[kg][srow][0] = hi;
            *(bf16x8*)&Al[kg][srow][0] = lo;
        }
        // ---- stage B (pre-split, contiguous copy) ----
#pragma unroll
        for (int rep = 0; rep < 2; ++rep) {
            const int s  = t + rep * 256;       // 0..511
            const int kg = s >> 7;
            const int nl = s & 127;
            const size_t src = ((((size_t)step * 4 + kg) * 256) + col0 + nl) * 8;
            *(bf16x8*)&Bh[kg][nl][0] = *(const bf16x8*)&WtHi[src];
            *(bf16x8*)&Bl[kg][nl][0] = *(const bf16x8*)&WtLo[src];
        }
        __syncthreads();

        // ---- fragments + MFMA ----
        bf16x8 ah[4], al[4];
#pragma unroll
        for (int i = 0; i < 4; ++i) {
            const int rl = wr * 64 + i * 16 + lrow;
            ah[i] = *(const bf16x8*)&Ah[kgf][rl][0];
            al[i] = *(const bf16x8*)&Al[kgf][rl][0];
        }
#pragma unroll
        for (int j = 0; j < 4; ++j) {
            const int cl = wc * 64 + j * 16 + lrow;
            const bf16x8 bh = *(const bf16x8*)&Bh[kgf][cl][0];
            const bf16x8 bl = *(const bf16x8*)&Bl[kgf][cl][0];
#pragma unroll
            for (int i = 0; i < 4; ++i) {
                acc[i][j] = __builtin_amdgcn_mfma_f32_16x16x32_bf16(al[i], bh, acc[i][j], 0, 0, 0);
                acc[i][j] = __builtin_amdgcn_mfma_f32_16x16x32_bf16(ah[i], bl, acc[i][j], 0, 0, 0);
                acc[i][j] = __builtin_amdgcn_mfma_f32_16x16x32_bf16(ah[i], bh, acc[i][j], 0, 0, 0);
            }
        }
        __syncthreads();
    }

    // ---- epilogue: C/D layout col=lane&15, row=(lane>>4)*4+r ----
    const int cbase = col0 + wc * 64 + lrow;
    const int rbase = row0 + wr * 64 + (lane >> 4) * 4;
#pragma unroll
    for (int i = 0; i < 4; ++i) {
#pragma unroll
        for (int r = 0; r < 4; ++r) {
            const int row = rbase + i * 16 + r;
            if (row < M) {
#pragma unroll
                for (int j = 0; j < 4; ++j)
                    H[(size_t)row * 256 + cbase + j * 16] = acc[i][j][r];
            }
        }
    }
}

// ---------------------------------------------------------------------------
// Per-node attention logits: a_src[n,h] = dot(h[n,h,:], att_src[h,:]) etc.
// ---------------------------------------------------------------------------
__global__ __launch_bounds__(256) void attdot_kernel(
    const float* __restrict__ H, const float* __restrict__ att_src,
    const float* __restrict__ att_dst, float* __restrict__ a_src,
    float* __restrict__ a_dst, int N)
{
    const int n = (int)((blockIdx.x * blockDim.x + threadIdx.x) >> 6);
    const int lane = threadIdx.x & 63;
    if (n >= N) return;
    const float4 hv = *(const float4*)(H + (size_t)n * 256 + lane * 4);
    const float4 as = *(const float4*)(att_src + lane * 4);
    const float4 ad = *(const float4*)(att_dst + lane * 4);
    float s = hv.x * as.x + hv.y * as.y + hv.z * as.z + hv.w * as.w;
    float d = hv.x * ad.x + hv.y * ad.y + hv.z * ad.z + hv.w * ad.w;
#pragma unroll
    for (int off = 1; off < 8; off <<= 1) {
        s += __shfl_xor(s, off);
        d += __shfl_xor(d, off);
    }
    if ((lane & 7) == 0) {
        a_src[(size_t)n * 8 + (lane >> 3)] = s;
        a_dst[(size_t)n * 8 + (lane >> 3)] = d;
    }
}

// ---------------------------------------------------------------------------
// Degree histogram over E2 = E + N edges (self-loops appended)
// ---------------------------------------------------------------------------
__global__ __launch_bounds__(256) void hist_kernel(
    const int* __restrict__ ei, int* __restrict__ deg, int E, int E2)
{
    const int e = blockIdx.x * blockDim.x + threadIdx.x;
    if (e >= E2) return;
    const int dst = (e < E) ? ei[(size_t)E + e] : (e - E);
    atomicAdd(&deg[dst], 1);
}

// ---------------------------------------------------------------------------
// Hierarchical exclusive scan (3 kernels): reduce -> scan partials -> final
// ---------------------------------------------------------------------------
__global__ __launch_bounds__(256) void scan_reduce_kernel(
    const int* __restrict__ deg, int* __restrict__ partial, int n)
{
    const int i = blockIdx.x * 256 + threadIdx.x;
    int v = (i < n) ? deg[i] : 0;
#pragma unroll
    for (int off = 1; off < 64; off <<= 1) v += __shfl_xor(v, off);
    __shared__ int s[4];
    if ((threadIdx.x & 63) == 0) s[threadIdx.x >> 6] = v;
    __syncthreads();
    if (threadIdx.x == 0) partial[blockIdx.x] = s[0] + s[1] + s[2] + s[3];
}

__global__ __launch_bounds__(256) void scan_partials_kernel(
    int* __restrict__ partial, int nb)
{
    __shared__ int tmp[256];
    const int t = threadIdx.x;
    const int v = (t < nb) ? partial[t] : 0;
    tmp[t] = v;
    __syncthreads();
    for (int off = 1; off < 256; off <<= 1) {
        int add = (t >= off) ? tmp[t - off] : 0;
        __syncthreads();
        tmp[t] += add;
        __syncthreads();
    }
    if (t < nb) partial[t] = tmp[t] - v;   // exclusive
}

__global__ __launch_bounds__(256) void scan_final_kernel(
    const int* __restrict__ deg, const int* __restrict__ partial,
    int* __restrict__ offsets, int n, int total)
{
    __shared__ int tmp[256];
    const int t = threadIdx.x;
    const int i = blockIdx.x * 256 + t;
    const int v = (i < n) ? deg[i] : 0;
    tmp[t] = v;
    __syncthreads();
    for (int off = 1; off < 256; off <<= 1) {
        int add = (t >= off) ? tmp[t - off] : 0;
        __syncthreads();
        tmp[t] += add;
        __syncthreads();
    }
    if (i < n) offsets[i] = partial[blockIdx.x] + tmp[t] - v;
    if (i == 0) offsets[n] = total;
}

// ---------------------------------------------------------------------------
// Scatter edges into CSR order (counting sort by dst)
// ---------------------------------------------------------------------------
__global__ __launch_bounds__(256) void scatter_kernel(
    const int* __restrict__ ei, const int* __restrict__ offsets,
    int* __restrict__ cursor, int* __restrict__ sorted_src, int E, int E2)
{
    const int e = blockIdx.x * blockDim.x + threadIdx.x;
    if (e >= E2) return;
    int src, dst;
    if (e < E) { src = ei[e]; dst = ei[(size_t)E + e]; }
    else       { src = e - E; dst = e - E; }
    const int pos = atomicAdd(&cursor[dst], 1);
    sorted_src[offsets[dst] + pos] = src;
}

// ---------------------------------------------------------------------------
// Aggregate: one wave per dst node. Online softmax (phase A) + weighted
// gather-accumulate (phase B, unroll 2) + bias + ELU.
// ---------------------------------------------------------------------------
__global__ __launch_bounds__(256) void aggregate_kernel(
    const float* __restrict__ H, const float* __restrict__ Asrc,
    const float* __restrict__ Adst, const int* __restrict__ offsets,
    const int* __restrict__ sorted_src, const float* __restrict__ bias,
    float* __restrict__ out, int N)
{
    const int n = (int)((blockIdx.x * blockDim.x + threadIdx.x) >> 6);
    const int lane = threadIdx.x & 63;
    if (n >= N) return;

    const int beg = offsets[n];
    const int deg = offsets[n + 1] - beg;

    const int h2 = lane & 7;
    const float adst2 = Adst[(size_t)n * 8 + h2];

    // phase A: online per-head (max, sum-of-exp)
    float m = -INFINITY;
    float ssum = 0.f;
    for (int i = lane; i < deg * 8; i += 64) {
        const int s = sorted_src[beg + (i >> 3)];
        float a = Asrc[(size_t)s * 8 + h2] + adst2;
        a = a > 0.f ? a : NEG_SLOPE * a;
        if (a > m) { ssum *= expf(m - a); m = a; }
        ssum += expf(a - m);
    }
#pragma unroll
    for (int off = 8; off < 64; off <<= 1) {
        const float mo = __shfl_xor(m, off);
        const float so = __shfl_xor(ssum, off);
        const float mn = fmaxf(m, mo);
        const float f1 = (m  <= -INFINITY) ? 0.f : expf(m  - mn);
        const float f2 = (mo <= -INFINITY) ? 0.f : expf(mo - mn);
        ssum = ssum * f1 + so * f2;
        m = mn;
    }

    // redistribute to phase-B head (lane>>3)
    const int h3 = lane >> 3;
    const float m3 = __shfl(m, h3);
    const float d3 = __shfl(ssum, h3);
    const float adst3 = __shfl(adst2, h3);
    const float rdn = 1.f / (d3 + 1e-16f);

    // phase B: acc = sum_e attn(e) * h[src_e][4l..4l+3], unrolled by 2
    float4 acc0 = make_float4(0.f, 0.f, 0.f, 0.f);
    float4 acc1 = make_float4(0.f, 0.f, 0.f, 0.f);
    int e = 0;
    for (; e + 2 <= deg; e += 2) {
        const int s0 = sorted_src[beg + e];
        const int s1 = sorted_src[beg + e + 1];
        float a0 = Asrc[(size_t)s0 * 8 + h3] + adst3;
        float a1 = Asrc[(size_t)s1 * 8 + h3] + adst3;
        a0 = a0 > 0.f ? a0 : NEG_SLOPE * a0;
        a1 = a1 > 0.f ? a1 : NEG_SLOPE * a1;
        const float w0 = expf(a0 - m3) * rdn;
        const float w1 = expf(a1 - m3) * rdn;
        const float4 h0 = *(const float4*)(H + (size_t)s0 * 256 + lane * 4);
        const float4 h1 = *(const float4*)(H + (size_t)s1 * 256 + lane * 4);
        acc0.x += h0.x * w0; acc0.y += h0.y * w0; acc0.z += h0.z * w0; acc0.w += h0.w * w0;
        acc1.x += h1.x * w1; acc1.y += h1.y * w1; acc1.z += h1.z * w1; acc1.w += h1.w * w1;
    }
    if (e < deg) {
        const int s0 = sorted_src[beg + e];
        float a0 = Asrc[(size_t)s0 * 8 + h3] + adst3;
        a0 = a0 > 0.f ? a0 : NEG_SLOPE * a0;
        const float w0 = expf(a0 - m3) * rdn;
        const float4 h0 = *(const float4*)(H + (size_t)s0 * 256 + lane * 4);
        acc0.x += h0.x * w0; acc0.y += h0.y * w0; acc0.z += h0.z * w0; acc0.w += h0.w * w0;
    }
    float4 acc;
    acc.x = acc0.x + acc1.x; acc.y = acc0.y + acc1.y;
    acc.z = acc0.z + acc1.z; acc.w = acc0.w + acc1.w;

    const float4 b = *(const float4*)(bias + lane * 4);
    float4 o;
    o.x = acc.x + b.x; o.y = acc.y + b.y; o.z = acc.z + b.z; o.w = acc.w + b.w;
    o.x = o.x > 0.f ? o.x : expf(o.x) - 1.f;
    o.y = o.y > 0.f ? o.y : expf(o.y) - 1.f;
    o.z = o.z > 0.f ? o.z : expf(o.z) - 1.f;
    o.w = o.w > 0.f ? o.w : expf(o.w) - 1.f;
    *(float4*)(out + (size_t)n * 256 + lane * 4) = o;
}

// ---------------------------------------------------------------------------
extern "C" void kernel_launch(void* const* d_in, const int* in_sizes, int n_in,
                              void* d_out, int out_size, void* d_ws, size_t ws_size,
                              hipStream_t stream)
{
    const float* x       = (const float*)d_in[0];
    const int*   ei      = (const int*)  d_in[1];
    const float* W       = (const float*)d_in[2];
    const float* att_src = (const float*)d_in[3];
    const float* att_dst = (const float*)d_in[4];
    const float* bias    = (const float*)d_in[5];
    float* out = (float*)d_out;

    const int N  = in_sizes[0] / F_IN;   // 50000
    const int E  = in_sizes[1] / 2;      // 800000
    const int E2 = E + N;                // + self loops
    const int NB = (N + 255) / 256;      // scan blocks

    // workspace layout (256B aligned sections)
    char* ws = (char*)d_ws;
    size_t o = 0;
    auto take = [&](size_t bytes) { void* p = ws + o; o = (o + bytes + 255) & ~(size_t)255; return p; };
    float* H          = (float*)take((size_t)N * 256 * 4);  // 51.2 MB
    float* a_src      = (float*)take((size_t)N * 8 * 4);
    float* a_dst      = (float*)take((size_t)N * 8 * 4);
    int*   deg        = (int*)  take((size_t)N * 4 * 2);    // deg + cursor adjacent
    int*   cursor     = deg + N;
    int*   offsets    = (int*)  take((size_t)(N + 1) * 4);
    int*   sorted_src = (int*)  take((size_t)E2 * 4);
    int*   partial    = (int*)  take((size_t)NB * 4);
    short* WtHi       = (short*)take((size_t)256 * 256 * 2);
    short* WtLo       = (short*)take((size_t)256 * 256 * 2);
    (void)ws_size; (void)n_in; (void)out_size;

    // 0) zero deg + cursor (ws is poisoned 0xAA before every call)
    hipMemsetAsync(deg, 0, (size_t)N * 4 * 2, stream);

    // 1) W split+tile, then H = x @ W via bf16x3 MFMA
    wprep_kernel<<<256, 256, 0, stream>>>(W, WtHi, WtLo);
    dim3 ggrid((N + 127) / 128, 2);
    gemm_mfma_kernel<<<ggrid, 256, 0, stream>>>(x, WtHi, WtLo, H, N);

    // 2) attention logits per node/head
    attdot_kernel<<<(N * 64 + 255) / 256, 256, 0, stream>>>(H, att_src, att_dst, a_src, a_dst, N);

    // 3) CSR build: histogram -> hierarchical scan -> scatter
    hist_kernel<<<(E2 + 255) / 256, 256, 0, stream>>>(ei, deg, E, E2);
    scan_reduce_kernel<<<NB, 256, 0, stream>>>(deg, partial, N);
    scan_partials_kernel<<<1, 256, 0, stream>>>(partial, NB);
    scan_final_kernel<<<NB, 256, 0, stream>>>(deg, partial, offsets, N, E2);
    scatter_kernel<<<(E2 + 255) / 256, 256, 0, stream>>>(ei, offsets, cursor, sorted_src, E, E2);

    // 4) softmax + aggregate + bias + ELU
    aggregate_kernel<<<(N * 64 + 255) / 256, 256, 0, stream>>>(H, a_src, a_dst, offsets, sorted_src, bias, out, N);
}

// Round 4
// 308.839 us; speedup vs baseline: 1.6255x; 1.1907x over previous
//
#include <hip/hip_runtime.h>
#include <hip/hip_bf16.h>
#include <math.h>

#define F_IN 256
#define HEADS 8
#define CPH 32
#define NEG_SLOPE 0.2f

typedef short bf16x8 __attribute__((ext_vector_type(8)));
typedef float f32x4  __attribute__((ext_vector_type(4)));
typedef _Float16 half4 __attribute__((ext_vector_type(4)));

// fp32 -> bf16 (RNE) as raw ushort bits
static __device__ __forceinline__ unsigned short f2bf(float f) {
    union { float f; unsigned int u; } v; v.f = f;
    unsigned int r = (v.u + 0x7FFFu + ((v.u >> 16) & 1u)) >> 16;
    return (unsigned short)r;
}
static __device__ __forceinline__ float bf2f(unsigned short h) {
    union { unsigned int u; float f; } v; v.u = ((unsigned int)h) << 16;
    return v.f;
}

// ---------------------------------------------------------------------------
// W prep: split W[k][n] fp32 into hi/lo bf16, pre-tiled for GEMM B-staging:
// Wt[sel][step][kg][n][j] = bf16(W[step*32 + kg*8 + j][n]);  sel=hi/lo
// ---------------------------------------------------------------------------
__global__ __launch_bounds__(256) void wprep_kernel(
    const float* __restrict__ W, short* __restrict__ WtHi, short* __restrict__ WtLo)
{
    const int k = blockIdx.x;      // 0..255
    const int n = threadIdx.x;     // 0..255
    const float w = W[(size_t)k * 256 + n];
    const unsigned short h = f2bf(w);
    const unsigned short l = f2bf(w - bf2f(h));
    const int step = k >> 5, kg = (k >> 3) & 3, j = k & 7;
    const size_t dst = ((((size_t)step * 4 + kg) * 256) + n) * 8 + j;
    WtHi[dst] = (short)h;
    WtLo[dst] = (short)l;
}

// ---------------------------------------------------------------------------
// GEMM: H = X[M,256] @ W[256,256] via bf16x3-split MFMA (fp32-accurate),
// output stored as fp16 (quantization <=1e-3, halves downstream gather BW).
// Block 256 thr = 4 waves (2x2), block tile 128x128, wave tile 64x64,
// K-step 32. LDS layout [kg][row][8 bf16], kg = k/8 = lane>>4.
// ---------------------------------------------------------------------------
__global__ __launch_bounds__(256, 2) void gemm_mfma_kernel(
    const float* __restrict__ X, const short* __restrict__ WtHi,
    const short* __restrict__ WtLo, _Float16* __restrict__ H2, int M)
{
    __shared__ short Ah[4][128][8];
    __shared__ short Al[4][128][8];
    __shared__ short Bh[4][128][8];
    __shared__ short Bl[4][128][8];

    const int t    = threadIdx.x;
    const int lane = t & 63;
    const int wid  = t >> 6;
    const int wr   = wid >> 1;          // wave row 0..1
    const int wc   = wid & 1;           // wave col 0..1
    const int row0 = blockIdx.x * 128;
    const int col0 = blockIdx.y * 128;

    const int srow  = t >> 1;           // staging row 0..127
    const int shalf = t & 1;            // which 16-k half

    f32x4 acc[4][4];
#pragma unroll
    for (int i = 0; i < 4; ++i)
#pragma unroll
        for (int j = 0; j < 4; ++j)
            acc[i][j] = (f32x4){0.f, 0.f, 0.f, 0.f};

    const int kgf = lane >> 4;          // fragment k-group
    const int lrow = lane & 15;

    for (int step = 0; step < 8; ++step) {
        const int k0 = step * 32;
        // ---- stage A (x split on the fly) ----
        float f[16];
        const int grow = row0 + srow;
        if (grow < M) {
            const float4* xp = (const float4*)(X + (size_t)grow * 256 + k0 + shalf * 16);
            const float4 v0 = xp[0], v1 = xp[1], v2 = xp[2], v3 = xp[3];
            f[0] = v0.x; f[1] = v0.y; f[2]  = v0.z; f[3]  = v0.w;
            f[4] = v1.x; f[5] = v1.y; f[6]  = v1.z; f[7]  = v1.w;
            f[8] = v2.x; f[9] = v2.y; f[10] = v2.z; f[11] = v2.w;
            f[12] = v3.x; f[13] = v3.y; f[14] = v3.z; f[15] = v3.w;
        } else {
#pragma unroll
            for (int j = 0; j < 16; ++j) f[j] = 0.f;
        }
#pragma unroll
        for (int c = 0; c < 2; ++c) {
            bf16x8 hi, lo;
#pragma unroll
            for (int j = 0; j < 8; ++j) {
                const float x = f[c * 8 + j];
                const unsigned short hb = f2bf(x);
                hi[j] = (short)hb;
                lo[j] = (short)f2bf(x - bf2f(hb));
            }
            const int kg = shalf * 2 + c;
            *(bf16x8*)&Ah[kg][srow][0] = hi;
            *(bf16x8*)&Al[kg][srow][0] = lo;
        }
        // ---- stage B (pre-split, contiguous copy) ----
#pragma unroll
        for (int rep = 0; rep < 2; ++rep) {
            const int s  = t + rep * 256;       // 0..511
            const int kg = s >> 7;
            const int nl = s & 127;
            const size_t src = ((((size_t)step * 4 + kg) * 256) + col0 + nl) * 8;
            *(bf16x8*)&Bh[kg][nl][0] = *(const bf16x8*)&WtHi[src];
            *(bf16x8*)&Bl[kg][nl][0] = *(const bf16x8*)&WtLo[src];
        }
        __syncthreads();

        // ---- fragments + MFMA ----
        bf16x8 ah[4], al[4];
#pragma unroll
        for (int i = 0; i < 4; ++i) {
            const int rl = wr * 64 + i * 16 + lrow;
            ah[i] = *(const bf16x8*)&Ah[kgf][rl][0];
            al[i] = *(const bf16x8*)&Al[kgf][rl][0];
        }
#pragma unroll
        for (int j = 0; j < 4; ++j) {
            const int cl = wc * 64 + j * 16 + lrow;
            const bf16x8 bh = *(const bf16x8*)&Bh[kgf][cl][0];
            const bf16x8 bl = *(const bf16x8*)&Bl[kgf][cl][0];
#pragma unroll
            for (int i = 0; i < 4; ++i) {
                acc[i][j] = __builtin_amdgcn_mfma_f32_16x16x32_bf16(al[i], bh, acc[i][j], 0, 0, 0);
                acc[i][j] = __builtin_amdgcn_mfma_f32_16x16x32_bf16(ah[i], bl, acc[i][j], 0, 0, 0);
                acc[i][j] = __builtin_amdgcn_mfma_f32_16x16x32_bf16(ah[i], bh, acc[i][j], 0, 0, 0);
            }
        }
        __syncthreads();
    }

    // ---- epilogue: C/D layout col=lane&15, row=(lane>>4)*4+r; fp16 store ----
    const int cbase = col0 + wc * 64 + lrow;
    const int rbase = row0 + wr * 64 + (lane >> 4) * 4;
#pragma unroll
    for (int i = 0; i < 4; ++i) {
#pragma unroll
        for (int r = 0; r < 4; ++r) {
            const int row = rbase + i * 16 + r;
            if (row < M) {
#pragma unroll
                for (int j = 0; j < 4; ++j)
                    H2[(size_t)row * 256 + cbase + j * 16] = (_Float16)acc[i][j][r];
            }
        }
    }
}

// ---------------------------------------------------------------------------
// Per-node attention logits from fp16 H
// ---------------------------------------------------------------------------
__global__ __launch_bounds__(256) void attdot_kernel(
    const _Float16* __restrict__ H2, const float* __restrict__ att_src,
    const float* __restrict__ att_dst, float* __restrict__ a_src,
    float* __restrict__ a_dst, int N)
{
    const int n = (int)((blockIdx.x * blockDim.x + threadIdx.x) >> 6);
    const int lane = threadIdx.x & 63;
    if (n >= N) return;
    const half4 hv = *(const half4*)(H2 + (size_t)n * 256 + lane * 4);
    const float4 as = *(const float4*)(att_src + lane * 4);
    const float4 ad = *(const float4*)(att_dst + lane * 4);
    const float h0 = (float)hv[0], h1 = (float)hv[1], h2 = (float)hv[2], h3 = (float)hv[3];
    float s = h0 * as.x + h1 * as.y + h2 * as.z + h3 * as.w;
    float d = h0 * ad.x + h1 * ad.y + h2 * ad.z + h3 * ad.w;
#pragma unroll
    for (int off = 1; off < 8; off <<= 1) {
        s += __shfl_xor(s, off);
        d += __shfl_xor(d, off);
    }
    if ((lane & 7) == 0) {
        a_src[(size_t)n * 8 + (lane >> 3)] = s;
        a_dst[(size_t)n * 8 + (lane >> 3)] = d;
    }
}

// ---------------------------------------------------------------------------
// Degree histogram over E2 = E + N edges (self-loops appended)
// ---------------------------------------------------------------------------
__global__ __launch_bounds__(256) void hist_kernel(
    const int* __restrict__ ei, int* __restrict__ deg, int E, int E2)
{
    const int e = blockIdx.x * blockDim.x + threadIdx.x;
    if (e >= E2) return;
    const int dst = (e < E) ? ei[(size_t)E + e] : (e - E);
    atomicAdd(&deg[dst], 1);
}

// ---------------------------------------------------------------------------
// Hierarchical exclusive scan (3 kernels): reduce -> scan partials -> final
// ---------------------------------------------------------------------------
__global__ __launch_bounds__(256) void scan_reduce_kernel(
    const int* __restrict__ deg, int* __restrict__ partial, int n)
{
    const int i = blockIdx.x * 256 + threadIdx.x;
    int v = (i < n) ? deg[i] : 0;
#pragma unroll
    for (int off = 1; off < 64; off <<= 1) v += __shfl_xor(v, off);
    __shared__ int s[4];
    if ((threadIdx.x & 63) == 0) s[threadIdx.x >> 6] = v;
    __syncthreads();
    if (threadIdx.x == 0) partial[blockIdx.x] = s[0] + s[1] + s[2] + s[3];
}

__global__ __launch_bounds__(256) void scan_partials_kernel(
    int* __restrict__ partial, int nb)
{
    __shared__ int tmp[256];
    const int t = threadIdx.x;
    const int v = (t < nb) ? partial[t] : 0;
    tmp[t] = v;
    __syncthreads();
    for (int off = 1; off < 256; off <<= 1) {
        int add = (t >= off) ? tmp[t - off] : 0;
        __syncthreads();
        tmp[t] += add;
        __syncthreads();
    }
    if (t < nb) partial[t] = tmp[t] - v;   // exclusive
}

__global__ __launch_bounds__(256) void scan_final_kernel(
    const int* __restrict__ deg, const int* __restrict__ partial,
    int* __restrict__ offsets, int n, int total)
{
    __shared__ int tmp[256];
    const int t = threadIdx.x;
    const int i = blockIdx.x * 256 + t;
    const int v = (i < n) ? deg[i] : 0;
    tmp[t] = v;
    __syncthreads();
    for (int off = 1; off < 256; off <<= 1) {
        int add = (t >= off) ? tmp[t - off] : 0;
        __syncthreads();
        tmp[t] += add;
        __syncthreads();
    }
    if (i < n) offsets[i] = partial[blockIdx.x] + tmp[t] - v;
    if (i == 0) offsets[n] = total;
}

// ---------------------------------------------------------------------------
// Scatter edges into CSR order (counting sort by dst)
// ---------------------------------------------------------------------------
__global__ __launch_bounds__(256) void scatter_kernel(
    const int* __restrict__ ei, const int* __restrict__ offsets,
    int* __restrict__ cursor, int* __restrict__ sorted_src, int E, int E2)
{
    const int e = blockIdx.x * blockDim.x + threadIdx.x;
    if (e >= E2) return;
    int src, dst;
    if (e < E) { src = ei[e]; dst = ei[(size_t)E + e]; }
    else       { src = e - E; dst = e - E; }
    const int pos = atomicAdd(&cursor[dst], 1);
    sorted_src[offsets[dst] + pos] = src;
}

// ---------------------------------------------------------------------------
// Aggregate: one wave per dst node. Online softmax (phase A) + fp16 weighted
// gather-accumulate (phase B, unroll 4) + bias + ELU.
// ---------------------------------------------------------------------------
__global__ __launch_bounds__(256) void aggregate_kernel(
    const _Float16* __restrict__ H2, const float* __restrict__ Asrc,
    const float* __restrict__ Adst, const int* __restrict__ offsets,
    const int* __restrict__ sorted_src, const float* __restrict__ bias,
    float* __restrict__ out, int N)
{
    const int n = (int)((blockIdx.x * blockDim.x + threadIdx.x) >> 6);
    const int lane = threadIdx.x & 63;
    if (n >= N) return;

    const int beg = offsets[n];
    const int deg = offsets[n + 1] - beg;

    const int h2 = lane & 7;
    const float adst2 = Adst[(size_t)n * 8 + h2];

    // phase A: online per-head (max, sum-of-exp)
    float m = -INFINITY;
    float ssum = 0.f;
    for (int i = lane; i < deg * 8; i += 64) {
        const int s = sorted_src[beg + (i >> 3)];
        float a = Asrc[(size_t)s * 8 + h2] + adst2;
        a = a > 0.f ? a : NEG_SLOPE * a;
        if (a > m) { ssum *= expf(m - a); m = a; }
        ssum += expf(a - m);
    }
#pragma unroll
    for (int off = 8; off < 64; off <<= 1) {
        const float mo = __shfl_xor(m, off);
        const float so = __shfl_xor(ssum, off);
        const float mn = fmaxf(m, mo);
        const float f1 = (m  <= -INFINITY) ? 0.f : expf(m  - mn);
        const float f2 = (mo <= -INFINITY) ? 0.f : expf(mo - mn);
        ssum = ssum * f1 + so * f2;
        m = mn;
    }

    // redistribute to phase-B head (lane>>3)
    const int h3 = lane >> 3;
    const float m3 = __shfl(m, h3);
    const float d3 = __shfl(ssum, h3);
    const float adst3 = __shfl(adst2, h3);
    const float rdn = 1.f / (d3 + 1e-16f);

    // phase B: acc = sum_e attn(e) * h[src_e][4l..4l+3], fp16 gather, unroll 4
    float4 acc0 = make_float4(0.f, 0.f, 0.f, 0.f);
    float4 acc1 = make_float4(0.f, 0.f, 0.f, 0.f);
    int e = 0;
    for (; e + 4 <= deg; e += 4) {
        const int s0 = sorted_src[beg + e];
        const int s1 = sorted_src[beg + e + 1];
        const int s2 = sorted_src[beg + e + 2];
        const int s3 = sorted_src[beg + e + 3];
        const half4 g0 = *(const half4*)(H2 + (size_t)s0 * 256 + lane * 4);
        const half4 g1 = *(const half4*)(H2 + (size_t)s1 * 256 + lane * 4);
        const half4 g2 = *(const half4*)(H2 + (size_t)s2 * 256 + lane * 4);
        const half4 g3 = *(const half4*)(H2 + (size_t)s3 * 256 + lane * 4);
        float a0 = Asrc[(size_t)s0 * 8 + h3] + adst3;
        float a1 = Asrc[(size_t)s1 * 8 + h3] + adst3;
        float a2 = Asrc[(size_t)s2 * 8 + h3] + adst3;
        float a3 = Asrc[(size_t)s3 * 8 + h3] + adst3;
        a0 = a0 > 0.f ? a0 : NEG_SLOPE * a0;
        a1 = a1 > 0.f ? a1 : NEG_SLOPE * a1;
        a2 = a2 > 0.f ? a2 : NEG_SLOPE * a2;
        a3 = a3 > 0.f ? a3 : NEG_SLOPE * a3;
        const float w0 = expf(a0 - m3) * rdn;
        const float w1 = expf(a1 - m3) * rdn;
        const float w2 = expf(a2 - m3) * rdn;
        const float w3 = expf(a3 - m3) * rdn;
        acc0.x += (float)g0[0] * w0; acc0.y += (float)g0[1] * w0; acc0.z += (float)g0[2] * w0; acc0.w += (float)g0[3] * w0;
        acc1.x += (float)g1[0] * w1; acc1.y += (float)g1[1] * w1; acc1.z += (float)g1[2] * w1; acc1.w += (float)g1[3] * w1;
        acc0.x += (float)g2[0] * w2; acc0.y += (float)g2[1] * w2; acc0.z += (float)g2[2] * w2; acc0.w += (float)g2[3] * w2;
        acc1.x += (float)g3[0] * w3; acc1.y += (float)g3[1] * w3; acc1.z += (float)g3[2] * w3; acc1.w += (float)g3[3] * w3;
    }
    for (; e < deg; ++e) {
        const int s0 = sorted_src[beg + e];
        const half4 g0 = *(const half4*)(H2 + (size_t)s0 * 256 + lane * 4);
        float a0 = Asrc[(size_t)s0 * 8 + h3] + adst3;
        a0 = a0 > 0.f ? a0 : NEG_SLOPE * a0;
        const float w0 = expf(a0 - m3) * rdn;
        acc0.x += (float)g0[0] * w0; acc0.y += (float)g0[1] * w0; acc0.z += (float)g0[2] * w0; acc0.w += (float)g0[3] * w0;
    }
    float4 acc;
    acc.x = acc0.x + acc1.x; acc.y = acc0.y + acc1.y;
    acc.z = acc0.z + acc1.z; acc.w = acc0.w + acc1.w;

    const float4 b = *(const float4*)(bias + lane * 4);
    float4 o;
    o.x = acc.x + b.x; o.y = acc.y + b.y; o.z = acc.z + b.z; o.w = acc.w + b.w;
    o.x = o.x > 0.f ? o.x : expf(o.x) - 1.f;
    o.y = o.y > 0.f ? o.y : expf(o.y) - 1.f;
    o.z = o.z > 0.f ? o.z : expf(o.z) - 1.f;
    o.w = o.w > 0.f ? o.w : expf(o.w) - 1.f;
    *(float4*)(out + (size_t)n * 256 + lane * 4) = o;
}

// ---------------------------------------------------------------------------
extern "C" void kernel_launch(void* const* d_in, const int* in_sizes, int n_in,
                              void* d_out, int out_size, void* d_ws, size_t ws_size,
                              hipStream_t stream)
{
    const float* x       = (const float*)d_in[0];
    const int*   ei      = (const int*)  d_in[1];
    const float* W       = (const float*)d_in[2];
    const float* att_src = (const float*)d_in[3];
    const float* att_dst = (const float*)d_in[4];
    const float* bias    = (const float*)d_in[5];
    float* out = (float*)d_out;

    const int N  = in_sizes[0] / F_IN;   // 50000
    const int E  = in_sizes[1] / 2;      // 800000
    const int E2 = E + N;                // + self loops
    const int NB = (N + 255) / 256;      // scan blocks

    // workspace layout (256B aligned sections)
    char* ws = (char*)d_ws;
    size_t o = 0;
    auto take = [&](size_t bytes) { void* p = ws + o; o = (o + bytes + 255) & ~(size_t)255; return p; };
    _Float16* H2      = (_Float16*)take((size_t)N * 256 * 2);  // 25.6 MB
    float* a_src      = (float*)take((size_t)N * 8 * 4);
    float* a_dst      = (float*)take((size_t)N * 8 * 4);
    int*   deg        = (int*)  take((size_t)N * 4 * 2);    // deg + cursor adjacent
    int*   cursor     = deg + N;
    int*   offsets    = (int*)  take((size_t)(N + 1) * 4);
    int*   sorted_src = (int*)  take((size_t)E2 * 4);
    int*   partial    = (int*)  take((size_t)NB * 4);
    short* WtHi       = (short*)take((size_t)256 * 256 * 2);
    short* WtLo       = (short*)take((size_t)256 * 256 * 2);
    (void)ws_size; (void)n_in; (void)out_size;

    // 0) zero deg + cursor (ws is poisoned 0xAA before every call)
    hipMemsetAsync(deg, 0, (size_t)N * 4 * 2, stream);

    // 1) W split+tile, then H = x @ W via bf16x3 MFMA, fp16 out
    wprep_kernel<<<256, 256, 0, stream>>>(W, WtHi, WtLo);
    dim3 ggrid((N + 127) / 128, 2);
    gemm_mfma_kernel<<<ggrid, 256, 0, stream>>>(x, WtHi, WtLo, H2, N);

    // 2) attention logits per node/head
    attdot_kernel<<<(N * 64 + 255) / 256, 256, 0, stream>>>(H2, att_src, att_dst, a_src, a_dst, N);

    // 3) CSR build: histogram -> hierarchical scan -> scatter
    hist_kernel<<<(E2 + 255) / 256, 256, 0, stream>>>(ei, deg, E, E2);
    scan_reduce_kernel<<<NB, 256, 0, stream>>>(deg, partial, N);
    scan_partials_kernel<<<1, 256, 0, stream>>>(partial, NB);
    scan_final_kernel<<<NB, 256, 0, stream>>>(deg, partial, offsets, N, E2);
    scatter_kernel<<<(E2 + 255) / 256, 256, 0, stream>>>(ei, offsets, cursor, sorted_src, E, E2);

    // 4) softmax + aggregate + bias + ELU
    aggregate_kernel<<<(N * 64 + 255) / 256, 256, 0, stream>>>(H2, a_src, a_dst, offsets, sorted_src, bias, out, N);
}

// Round 5
// 300.265 us; speedup vs baseline: 1.6719x; 1.0286x over previous
//
#include <hip/hip_runtime.h>
#include <hip/hip_bf16.h>
#include <math.h>

#define F_IN 256
#define HEADS 8
#define CPH 32
#define NEG_SLOPE 0.2f
#define MAXD 128

typedef short bf16x8 __attribute__((ext_vector_type(8)));
typedef float f32x4  __attribute__((ext_vector_type(4)));
typedef _Float16 half4 __attribute__((ext_vector_type(4)));

// fp32 -> bf16 (RNE) as raw ushort bits
static __device__ __forceinline__ unsigned short f2bf(float f) {
    union { float f; unsigned int u; } v; v.f = f;
    unsigned int r = (v.u + 0x7FFFu + ((v.u >> 16) & 1u)) >> 16;
    return (unsigned short)r;
}
static __device__ __forceinline__ float bf2f(unsigned short h) {
    union { unsigned int u; float f; } v; v.u = ((unsigned int)h) << 16;
    return v.f;
}

// wave-local LDS ordering fence (guide rule #18)
static __device__ __forceinline__ void lds_fence() {
    asm volatile("s_waitcnt lgkmcnt(0)" ::: "memory");
    __builtin_amdgcn_sched_barrier(0);
}

// ---------------------------------------------------------------------------
// W prep: split W[k][n] fp32 into hi/lo bf16, pre-tiled for GEMM B-staging
// ---------------------------------------------------------------------------
__global__ __launch_bounds__(256) void wprep_kernel(
    const float* __restrict__ W, short* __restrict__ WtHi, short* __restrict__ WtLo)
{
    const int k = blockIdx.x;      // 0..255
    const int n = threadIdx.x;     // 0..255
    const float w = W[(size_t)k * 256 + n];
    const unsigned short h = f2bf(w);
    const unsigned short l = f2bf(w - bf2f(h));
    const int step = k >> 5, kg = (k >> 3) & 3, j = k & 7;
    const size_t dst = ((((size_t)step * 4 + kg) * 256) + n) * 8 + j;
    WtHi[dst] = (short)h;
    WtLo[dst] = (short)l;
}

// ---------------------------------------------------------------------------
// GEMM: H = X[M,256] @ W[256,256] via bf16x3-split MFMA, fp16 output.
// ---------------------------------------------------------------------------
__global__ __launch_bounds__(256, 2) void gemm_mfma_kernel(
    const float* __restrict__ X, const short* __restrict__ WtHi,
    const short* __restrict__ WtLo, _Float16* __restrict__ H2, int M)
{
    __shared__ short Ah[4][128][8];
    __shared__ short Al[4][128][8];
    __shared__ short Bh[4][128][8];
    __shared__ short Bl[4][128][8];

    const int t    = threadIdx.x;
    const int lane = t & 63;
    const int wid  = t >> 6;
    const int wr   = wid >> 1;
    const int wc   = wid & 1;
    const int row0 = blockIdx.x * 128;
    const int col0 = blockIdx.y * 128;

    const int srow  = t >> 1;
    const int shalf = t & 1;

    f32x4 acc[4][4];
#pragma unroll
    for (int i = 0; i < 4; ++i)
#pragma unroll
        for (int j = 0; j < 4; ++j)
            acc[i][j] = (f32x4){0.f, 0.f, 0.f, 0.f};

    const int kgf = lane >> 4;
    const int lrow = lane & 15;

    for (int step = 0; step < 8; ++step) {
        const int k0 = step * 32;
        float f[16];
        const int grow = row0 + srow;
        if (grow < M) {
            const float4* xp = (const float4*)(X + (size_t)grow * 256 + k0 + shalf * 16);
            const float4 v0 = xp[0], v1 = xp[1], v2 = xp[2], v3 = xp[3];
            f[0] = v0.x; f[1] = v0.y; f[2]  = v0.z; f[3]  = v0.w;
            f[4] = v1.x; f[5] = v1.y; f[6]  = v1.z; f[7]  = v1.w;
            f[8] = v2.x; f[9] = v2.y; f[10] = v2.z; f[11] = v2.w;
            f[12] = v3.x; f[13] = v3.y; f[14] = v3.z; f[15] = v3.w;
        } else {
#pragma unroll
            for (int j = 0; j < 16; ++j) f[j] = 0.f;
        }
#pragma unroll
        for (int c = 0; c < 2; ++c) {
            bf16x8 hi, lo;
#pragma unroll
            for (int j = 0; j < 8; ++j) {
                const float x = f[c * 8 + j];
                const unsigned short hb = f2bf(x);
                hi[j] = (short)hb;
                lo[j] = (short)f2bf(x - bf2f(hb));
            }
            const int kg = shalf * 2 + c;
            *(bf16x8*)&Ah[kg][srow][0] = hi;
            *(bf16x8*)&Al[kg][srow][0] = lo;
        }
#pragma unroll
        for (int rep = 0; rep < 2; ++rep) {
            const int s  = t + rep * 256;
            const int kg = s >> 7;
            const int nl = s & 127;
            const size_t src = ((((size_t)step * 4 + kg) * 256) + col0 + nl) * 8;
            *(bf16x8*)&Bh[kg][nl][0] = *(const bf16x8*)&WtHi[src];
            *(bf16x8*)&Bl[kg][nl][0] = *(const bf16x8*)&WtLo[src];
        }
        __syncthreads();

        bf16x8 ah[4], al[4];
#pragma unroll
        for (int i = 0; i < 4; ++i) {
            const int rl = wr * 64 + i * 16 + lrow;
            ah[i] = *(const bf16x8*)&Ah[kgf][rl][0];
            al[i] = *(const bf16x8*)&Al[kgf][rl][0];
        }
#pragma unroll
        for (int j = 0; j < 4; ++j) {
            const int cl = wc * 64 + j * 16 + lrow;
            const bf16x8 bh = *(const bf16x8*)&Bh[kgf][cl][0];
            const bf16x8 bl = *(const bf16x8*)&Bl[kgf][cl][0];
#pragma unroll
            for (int i = 0; i < 4; ++i) {
                acc[i][j] = __builtin_amdgcn_mfma_f32_16x16x32_bf16(al[i], bh, acc[i][j], 0, 0, 0);
                acc[i][j] = __builtin_amdgcn_mfma_f32_16x16x32_bf16(ah[i], bl, acc[i][j], 0, 0, 0);
                acc[i][j] = __builtin_amdgcn_mfma_f32_16x16x32_bf16(ah[i], bh, acc[i][j], 0, 0, 0);
            }
        }
        __syncthreads();
    }

    const int cbase = col0 + wc * 64 + lrow;
    const int rbase = row0 + wr * 64 + (lane >> 4) * 4;
#pragma unroll
    for (int i = 0; i < 4; ++i) {
#pragma unroll
        for (int r = 0; r < 4; ++r) {
            const int row = rbase + i * 16 + r;
            if (row < M) {
#pragma unroll
                for (int j = 0; j < 4; ++j)
                    H2[(size_t)row * 256 + cbase + j * 16] = (_Float16)acc[i][j][r];
            }
        }
    }
}

// ---------------------------------------------------------------------------
// Per-node attention logits from fp16 H
// ---------------------------------------------------------------------------
__global__ __launch_bounds__(256) void attdot_kernel(
    const _Float16* __restrict__ H2, const float* __restrict__ att_src,
    const float* __restrict__ att_dst, float* __restrict__ a_src,
    float* __restrict__ a_dst, int N)
{
    const int n = (int)((blockIdx.x * blockDim.x + threadIdx.x) >> 6);
    const int lane = threadIdx.x & 63;
    if (n >= N) return;
    const half4 hv = *(const half4*)(H2 + (size_t)n * 256 + lane * 4);
    const float4 as = *(const float4*)(att_src + lane * 4);
    const float4 ad = *(const float4*)(att_dst + lane * 4);
    const float h0 = (float)hv[0], h1 = (float)hv[1], h2 = (float)hv[2], h3 = (float)hv[3];
    float s = h0 * as.x + h1 * as.y + h2 * as.z + h3 * as.w;
    float d = h0 * ad.x + h1 * ad.y + h2 * ad.z + h3 * ad.w;
#pragma unroll
    for (int off = 1; off < 8; off <<= 1) {
        s += __shfl_xor(s, off);
        d += __shfl_xor(d, off);
    }
    if ((lane & 7) == 0) {
        a_src[(size_t)n * 8 + (lane >> 3)] = s;
        a_dst[(size_t)n * 8 + (lane >> 3)] = d;
    }
}

// ---------------------------------------------------------------------------
// Degree histogram
// ---------------------------------------------------------------------------
__global__ __launch_bounds__(256) void hist_kernel(
    const int* __restrict__ ei, int* __restrict__ deg, int E, int E2)
{
    const int e = blockIdx.x * blockDim.x + threadIdx.x;
    if (e >= E2) return;
    const int dst = (e < E) ? ei[(size_t)E + e] : (e - E);
    atomicAdd(&deg[dst], 1);
}

// ---------------------------------------------------------------------------
// Hierarchical exclusive scan
// ---------------------------------------------------------------------------
__global__ __launch_bounds__(256) void scan_reduce_kernel(
    const int* __restrict__ deg, int* __restrict__ partial, int n)
{
    const int i = blockIdx.x * 256 + threadIdx.x;
    int v = (i < n) ? deg[i] : 0;
#pragma unroll
    for (int off = 1; off < 64; off <<= 1) v += __shfl_xor(v, off);
    __shared__ int s[4];
    if ((threadIdx.x & 63) == 0) s[threadIdx.x >> 6] = v;
    __syncthreads();
    if (threadIdx.x == 0) partial[blockIdx.x] = s[0] + s[1] + s[2] + s[3];
}

__global__ __launch_bounds__(256) void scan_partials_kernel(
    int* __restrict__ partial, int nb)
{
    __shared__ int tmp[256];
    const int t = threadIdx.x;
    const int v = (t < nb) ? partial[t] : 0;
    tmp[t] = v;
    __syncthreads();
    for (int off = 1; off < 256; off <<= 1) {
        int add = (t >= off) ? tmp[t - off] : 0;
        __syncthreads();
        tmp[t] += add;
        __syncthreads();
    }
    if (t < nb) partial[t] = tmp[t] - v;   // exclusive
}

__global__ __launch_bounds__(256) void scan_final_kernel(
    const int* __restrict__ deg, const int* __restrict__ partial,
    int* __restrict__ offsets, int n, int total)
{
    __shared__ int tmp[256];
    const int t = threadIdx.x;
    const int i = blockIdx.x * 256 + t;
    const int v = (i < n) ? deg[i] : 0;
    tmp[t] = v;
    __syncthreads();
    for (int off = 1; off < 256; off <<= 1) {
        int add = (t >= off) ? tmp[t - off] : 0;
        __syncthreads();
        tmp[t] += add;
        __syncthreads();
    }
    if (i < n) offsets[i] = partial[blockIdx.x] + tmp[t] - v;
    if (i == 0) offsets[n] = total;
}

// ---------------------------------------------------------------------------
// Scatter edges into CSR order
// ---------------------------------------------------------------------------
__global__ __launch_bounds__(256) void scatter_kernel(
    const int* __restrict__ ei, const int* __restrict__ offsets,
    int* __restrict__ cursor, int* __restrict__ sorted_src, int E, int E2)
{
    const int e = blockIdx.x * blockDim.x + threadIdx.x;
    if (e >= E2) return;
    int src, dst;
    if (e < E) { src = ei[e]; dst = ei[(size_t)E + e]; }
    else       { src = e - E; dst = e - E; }
    const int pos = atomicAdd(&cursor[dst], 1);
    sorted_src[offsets[dst] + pos] = src;
}

// ---------------------------------------------------------------------------
// Aggregate: one wave per dst node.
// Sweep 1: alpha -> LDS, track per-head max (no exp).
// Sweep 2: w = __expf(alpha - m) once per (edge,head), accumulate sum.
// Sweep 3: normalize w in LDS.
// Phase B: broadcast w + src-id from LDS, fp16 gather, fma. No per-lane exp.
// deg > MAXD falls back to recompute path (correct for any input).
// ---------------------------------------------------------------------------
__global__ __launch_bounds__(256) void aggregate_kernel(
    const _Float16* __restrict__ H2, const float* __restrict__ Asrc,
    const float* __restrict__ Adst, const int* __restrict__ offsets,
    const int* __restrict__ sorted_src, const float* __restrict__ bias,
    float* __restrict__ out, int N)
{
    __shared__ float aw[4][MAXD][8];
    __shared__ int   sid[4][MAXD];

    const int n = (int)((blockIdx.x * blockDim.x + threadIdx.x) >> 6);
    const int lane = threadIdx.x & 63;
    const int wid  = (threadIdx.x >> 6) & 3;
    if (n >= N) return;

    const int beg = offsets[n];
    const int deg = offsets[n + 1] - beg;
    const int dcap = deg < MAXD ? deg : MAXD;

    const int h2 = lane & 7;
    const float adst2 = Adst[(size_t)n * 8 + h2];

    // sweep 1: alpha -> LDS, per-head max
    float m = -INFINITY;
    for (int i = lane; i < deg * 8; i += 64) {
        const int e = i >> 3;
        const int s = sorted_src[beg + e];
        float a = Asrc[(size_t)s * 8 + h2] + adst2;
        a = a > 0.f ? a : NEG_SLOPE * a;
        if (e < MAXD) {
            aw[wid][e][h2] = a;
            if (h2 == 0) sid[wid][e] = s;
        }
        m = fmaxf(m, a);
    }
#pragma unroll
    for (int off = 8; off < 64; off <<= 1) m = fmaxf(m, __shfl_xor(m, off));
    lds_fence();

    // sweep 2: w = exp(alpha - m), sum
    float ssum = 0.f;
    for (int i = lane; i < deg * 8; i += 64) {
        const int e = i >> 3;
        float a;
        if (e < MAXD) {
            a = aw[wid][e][h2];
        } else {
            const int s = sorted_src[beg + e];
            a = Asrc[(size_t)s * 8 + h2] + adst2;
            a = a > 0.f ? a : NEG_SLOPE * a;
        }
        const float w = __expf(a - m);
        ssum += w;
        if (e < MAXD) aw[wid][e][h2] = w;
    }
#pragma unroll
    for (int off = 8; off < 64; off <<= 1) ssum += __shfl_xor(ssum, off);
    const float rdn = 1.f / (ssum + 1e-16f);
    lds_fence();

    // sweep 3: normalize in LDS
    for (int i = lane; i < dcap * 8; i += 64)
        aw[wid][i >> 3][h2] *= rdn;
    lds_fence();

    // phase B
    const int h3 = lane >> 3;
    const float m3   = __shfl(m, h3);
    const float rdn3 = __shfl(rdn, h3);
    const float adst3 = __shfl(adst2, h3);

    float4 acc0 = make_float4(0.f, 0.f, 0.f, 0.f);
    float4 acc1 = make_float4(0.f, 0.f, 0.f, 0.f);
    int e = 0;
    for (; e + 4 <= dcap; e += 4) {
        const int4 s4 = *(const int4*)&sid[wid][e];
        const float w0 = aw[wid][e + 0][h3];
        const float w1 = aw[wid][e + 1][h3];
        const float w2 = aw[wid][e + 2][h3];
        const float w3 = aw[wid][e + 3][h3];
        const half4 g0 = *(const half4*)(H2 + (size_t)s4.x * 256 + lane * 4);
        const half4 g1 = *(const half4*)(H2 + (size_t)s4.y * 256 + lane * 4);
        const half4 g2 = *(const half4*)(H2 + (size_t)s4.z * 256 + lane * 4);
        const half4 g3 = *(const half4*)(H2 + (size_t)s4.w * 256 + lane * 4);
        acc0.x += (float)g0[0] * w0; acc0.y += (float)g0[1] * w0; acc0.z += (float)g0[2] * w0; acc0.w += (float)g0[3] * w0;
        acc1.x += (float)g1[0] * w1; acc1.y += (float)g1[1] * w1; acc1.z += (float)g1[2] * w1; acc1.w += (float)g1[3] * w1;
        acc0.x += (float)g2[0] * w2; acc0.y += (float)g2[1] * w2; acc0.z += (float)g2[2] * w2; acc0.w += (float)g2[3] * w2;
        acc1.x += (float)g3[0] * w3; acc1.y += (float)g3[1] * w3; acc1.z += (float)g3[2] * w3; acc1.w += (float)g3[3] * w3;
    }
    for (; e < dcap; ++e) {
        const int s0 = sid[wid][e];
        const float w0 = aw[wid][e][h3];
        const half4 g0 = *(const half4*)(H2 + (size_t)s0 * 256 + lane * 4);
        acc0.x += (float)g0[0] * w0; acc0.y += (float)g0[1] * w0; acc0.z += (float)g0[2] * w0; acc0.w += (float)g0[3] * w0;
    }
    // fallback: edges beyond LDS capacity (never hit for this input's degrees)
    for (; e < deg; ++e) {
        const int s0 = sorted_src[beg + e];
        float a0 = Asrc[(size_t)s0 * 8 + h3] + adst3;
        a0 = a0 > 0.f ? a0 : NEG_SLOPE * a0;
        const float w0 = __expf(a0 - m3) * rdn3;
        const half4 g0 = *(const half4*)(H2 + (size_t)s0 * 256 + lane * 4);
        acc0.x += (float)g0[0] * w0; acc0.y += (float)g0[1] * w0; acc0.z += (float)g0[2] * w0; acc0.w += (float)g0[3] * w0;
    }
    float4 acc;
    acc.x = acc0.x + acc1.x; acc.y = acc0.y + acc1.y;
    acc.z = acc0.z + acc1.z; acc.w = acc0.w + acc1.w;

    const float4 b = *(const float4*)(bias + lane * 4);
    float4 o;
    o.x = acc.x + b.x; o.y = acc.y + b.y; o.z = acc.z + b.z; o.w = acc.w + b.w;
    o.x = o.x > 0.f ? o.x : __expf(o.x) - 1.f;
    o.y = o.y > 0.f ? o.y : __expf(o.y) - 1.f;
    o.z = o.z > 0.f ? o.z : __expf(o.z) - 1.f;
    o.w = o.w > 0.f ? o.w : __expf(o.w) - 1.f;
    *(float4*)(out + (size_t)n * 256 + lane * 4) = o;
}

// ---------------------------------------------------------------------------
extern "C" void kernel_launch(void* const* d_in, const int* in_sizes, int n_in,
                              void* d_out, int out_size, void* d_ws, size_t ws_size,
                              hipStream_t stream)
{
    const float* x       = (const float*)d_in[0];
    const int*   ei      = (const int*)  d_in[1];
    const float* W       = (const float*)d_in[2];
    const float* att_src = (const float*)d_in[3];
    const float* att_dst = (const float*)d_in[4];
    const float* bias    = (const float*)d_in[5];
    float* out = (float*)d_out;

    const int N  = in_sizes[0] / F_IN;   // 50000
    const int E  = in_sizes[1] / 2;      // 800000
    const int E2 = E + N;                // + self loops
    const int NB = (N + 255) / 256;      // scan blocks

    // workspace layout (256B aligned sections)
    char* ws = (char*)d_ws;
    size_t o = 0;
    auto take = [&](size_t bytes) { void* p = ws + o; o = (o + bytes + 255) & ~(size_t)255; return p; };
    _Float16* H2      = (_Float16*)take((size_t)N * 256 * 2);  // 25.6 MB
    float* a_src      = (float*)take((size_t)N * 8 * 4);
    float* a_dst      = (float*)take((size_t)N * 8 * 4);
    int*   deg        = (int*)  take((size_t)N * 4 * 2);    // deg + cursor adjacent
    int*   cursor     = deg + N;
    int*   offsets    = (int*)  take((size_t)(N + 1) * 4);
    int*   sorted_src = (int*)  take((size_t)E2 * 4);
    int*   partial    = (int*)  take((size_t)NB * 4);
    short* WtHi       = (short*)take((size_t)256 * 256 * 2);
    short* WtLo       = (short*)take((size_t)256 * 256 * 2);
    (void)ws_size; (void)n_in; (void)out_size;

    // 0) zero deg + cursor
    hipMemsetAsync(deg, 0, (size_t)N * 4 * 2, stream);

    // 1) W split+tile, then H = x @ W via bf16x3 MFMA, fp16 out
    wprep_kernel<<<256, 256, 0, stream>>>(W, WtHi, WtLo);
    dim3 ggrid((N + 127) / 128, 2);
    gemm_mfma_kernel<<<ggrid, 256, 0, stream>>>(x, WtHi, WtLo, H2, N);

    // 2) attention logits per node/head
    attdot_kernel<<<(N * 64 + 255) / 256, 256, 0, stream>>>(H2, att_src, att_dst, a_src, a_dst, N);

    // 3) CSR build: histogram -> hierarchical scan -> scatter
    hist_kernel<<<(E2 + 255) / 256, 256, 0, stream>>>(ei, deg, E, E2);
    scan_reduce_kernel<<<NB, 256, 0, stream>>>(deg, partial, N);
    scan_partials_kernel<<<1, 256, 0, stream>>>(partial, NB);
    scan_final_kernel<<<NB, 256, 0, stream>>>(deg, partial, offsets, N, E2);
    scatter_kernel<<<(E2 + 255) / 256, 256, 0, stream>>>(ei, offsets, cursor, sorted_src, E, E2);

    // 4) softmax + aggregate + bias + ELU
    aggregate_kernel<<<(N * 64 + 255) / 256, 256, 0, stream>>>(H2, a_src, a_dst, offsets, sorted_src, bias, out, N);
}